// Round 2
// baseline (233.813 us; speedup 1.0000x reference)
//
#include <hip/hip_runtime.h>

// out[b, s*3+c, ph, pw] = img[c, (ys[b*2+s]+ph)&4095, (xs[b*2+s]+pw)&4095]
//
// Block = one (b, cc) tile: blockIdx.x = t = b*6 + cc  (1536 blocks).
// All patch/channel indexing is wave-uniform -> scalar regs + s_load.
// Each of the 256 threads produces one float4 of the 32x32 tile.

__global__ __launch_bounds__(256) void patch_gather_kernel(
    const float* __restrict__ img,
    const int*   __restrict__ ys,
    const int*   __restrict__ xs,
    float*       __restrict__ out)
{
    const int t  = blockIdx.x;          // b*6 + cc, uniform per block
    const int b  = t / 6;               // scalar magic-mul
    const int cc = t - b * 6;           // s*3 + c
    const int s  = (cc >= 3) ? 1 : 0;
    const int c  = cc - s * 3;
    const int n  = b * 2 + s;

    const int sy = ys[n];               // uniform -> scalar load
    const int sx = xs[n];

    const int lane = threadIdx.x;       // 0..255
    const int ph   = lane >> 3;         // 0..31
    const int pw0  = (lane & 7) * 4;    // 0,4,...,28

    const int y  = (sy + ph) & 4095;
    const int xb = sx + pw0;

    const float* __restrict__ row =
        img + (((size_t)c << 12) + (size_t)y) * 4096;

    float4 v;
    v.x = row[(xb    ) & 4095];
    v.y = row[(xb + 1) & 4095];
    v.z = row[(xb + 2) & 4095];
    v.w = row[(xb + 3) & 4095];

    float* o = out + ((size_t)t << 10) + (size_t)lane * 4;
    __builtin_nontemporal_store(v.x, o + 0);
    __builtin_nontemporal_store(v.y, o + 1);
    __builtin_nontemporal_store(v.z, o + 2);
    __builtin_nontemporal_store(v.w, o + 3);
}

extern "C" void kernel_launch(void* const* d_in, const int* in_sizes, int n_in,
                              void* d_out, int out_size, void* d_ws, size_t ws_size,
                              hipStream_t stream)
{
    const float* img = (const float*)d_in[0];   // [1,3,4096,4096] fp32
    const int*   ys  = (const int*)d_in[1];     // [512]
    const int*   xs  = (const int*)d_in[2];     // [512]
    float*       out = (float*)d_out;           // [256,6,32,32] fp32

    const int blocks = out_size / 1024;         // 1536 tiles
    patch_gather_kernel<<<blocks, 256, 0, stream>>>(img, ys, xs, out);
}